// Round 1
// 1309.786 us; speedup vs baseline: 1.2699x; 1.2699x over previous
//
#include <hip/hip_runtime.h>

// db6 filter taps
#define D0  -0.00107730108499558f
#define D1   0.004777257511010651f
#define D2   0.0005538422009938016f
#define D3  -0.031582039318031156f
#define D4   0.02752286553001629f
#define D5   0.09750160558707936f
#define D6  -0.12976686756709563f
#define D7  -0.22626469396516913f
#define D8   0.3152503517092432f
#define D9   0.7511339080215775f
#define D10  0.4946238903983854f
#define D11  0.11154074335008017f

// a_lo = rec_lo = reversed(dec_lo); a_hi = dec_lo with odd idx negated
// s_lo = dec_lo; s_hi[i] = dec_lo[11-i] * (i even ? -1 : +1)
__constant__ float c_ALO[12] = { D11, D10, D9, D8, D7, D6, D5, D4, D3, D2, D1, D0 };
__constant__ float c_AHI[12] = { D0, -D1, D2, -D3, D4, -D5, D6, -D7, D8, -D9, D10, -D11 };
__constant__ float c_SLO[12] = { D0, D1, D2, D3, D4, D5, D6, D7, D8, D9, D10, D11 };
__constant__ float c_SHI[12] = { -D11, D10, -D9, D8, -D7, D6, -D5, D4, -D3, D2, -D1, D0 };

#define NB 512  // B*C = 8*64

// ---------------- DWT analysis ----------------

// Level-1 row pass, fused NCHW -> channel-last. x:[512,256,256] -> lo,hi:[256,133,512]
// Tiled: block = (h, 32-channel slab). Coalesced float4 loads of 32 full rows into
// LDS (pad 257 -> bank = (nl+j)%32, worst 2-way = free), then all 133 outputs
// computed from LDS, written channel-contiguous.
__global__ __launch_bounds__(256) void k_afb_rows_nchw(
    const float* __restrict__ x, float* __restrict__ lo, float* __restrict__ hi) {
  __shared__ float lds[32][257];
  int h = blockIdx.x >> 4;          // 256 h values
  int n0 = (blockIdx.x & 15) << 5;  // 16 slabs of 32 channels
  // load 32 rows x 256 floats, fully coalesced float4
  for (int idx = threadIdx.x; idx < 32 * 64; idx += 256) {
    int r = idx >> 6, c4 = idx & 63;
    float4 v = *(const float4*)(x + ((long)(n0 + r) * 256 + h) * 256 + (c4 << 2));
    int c = c4 << 2;
    lds[r][c] = v.x; lds[r][c + 1] = v.y; lds[r][c + 2] = v.z; lds[r][c + 3] = v.w;
  }
  __syncthreads();
  int nl = threadIdx.x & 31;
  for (int k = threadIdx.x >> 5; k < 133; k += 8) {
    int base = 2 * k - 10;
    float aL = 0.f, aH = 0.f;
#pragma unroll
    for (int t = 0; t < 12; ++t) {
      int j = base + t;
      j = (j < 0) ? (-j - 1) : ((j >= 256) ? (511 - j) : j);
      float v = lds[nl][j];
      aL += v * c_ALO[t];
      aH += v * c_AHI[t];
    }
    long ob = ((long)h * 133 + k) * NB + n0 + nl;
    lo[ob] = aL;
    hi[ob] = aH;
  }
}

// Row-analysis on channel-last [H, Win, 512] -> [H, outW, 512]
__global__ __launch_bounds__(256) void k_afb_rows_cl(
    const float* __restrict__ in, float* __restrict__ lo, float* __restrict__ hi,
    int Win, int outW, int padL) {
  int blk = blockIdx.x;
  int h = blk / outW, k = blk - h * outW;
  int base = 2 * k - padL;
  const float* rowb = in + (long)h * Win * NB;
  long obase = ((long)h * outW + k) * NB;
  for (int n = threadIdx.x; n < NB; n += 256) {
    float aL = 0.f, aH = 0.f;
#pragma unroll
    for (int t = 0; t < 12; ++t) {
      int j = base + t;
      j = (j < 0) ? (-j - 1) : ((j >= Win) ? (2 * Win - 1 - j) : j);
      float v = rowb[(long)j * NB + n];
      aL += v * c_ALO[t];
      aH += v * c_AHI[t];
    }
    lo[obase + n] = aL;
    hi[obase + n] = aH;
  }
}

// Column-analysis on channel-last [Hin, W, 512] -> [outH, W, 512]
__global__ __launch_bounds__(256) void k_afb_cols_cl(
    const float* __restrict__ in, float* __restrict__ lo, float* __restrict__ hi,
    int Hin, int W, int outH, int padL) {
  int blk = blockIdx.x;
  int k = blk / W, w = blk - k * W;
  int base = 2 * k - padL;
  long rstride = (long)W * NB;
  const float* colb = in + (long)w * NB;
  long obase = ((long)k * W + w) * NB;
  for (int n = threadIdx.x; n < NB; n += 256) {
    float aL = 0.f, aH = 0.f;
#pragma unroll
    for (int t = 0; t < 12; ++t) {
      int j = base + t;
      j = (j < 0) ? (-j - 1) : ((j >= Hin) ? (2 * Hin - 1 - j) : j);
      float v = colb[(long)j * rstride + n];
      aL += v * c_ALO[t];
      aH += v * c_AHI[t];
    }
    lo[obase + n] = aL;
    hi[obase + n] = aH;
  }
}

// ---------------- IDWT synthesis ----------------
// out[m] = sum_t u_pad[m+t]*S[t]; u is zero-upsampled (u[2j]=in[j]), pad 1 each side.
// contributing taps: t with (m+t-1) even, j=(m+t-1)/2 in [0,n)

// Column-synthesis: lo,hi (rows j, width W, CL) -> out [2n-10, W, 512] packed
__global__ __launch_bounds__(256) void k_sfb_cols_cl(
    const float* __restrict__ lo, long lors, const float* __restrict__ hi, long hirs,
    float* __restrict__ out, int n, int W, int outH) {
  int blk = blockIdx.x;
  int m = blk / W, w = blk - m * W;
  int t0 = 1 - (m & 1);
  const float* lob = lo + (long)w * NB;
  const float* hib = hi + (long)w * NB;
  long obase = ((long)m * W + w) * NB;
  for (int nn = threadIdx.x; nn < NB; nn += 256) {
    float acc = 0.f;
#pragma unroll
    for (int s6 = 0; s6 < 6; ++s6) {
      int t = t0 + 2 * s6;
      int j = (m + t - 1) >> 1;
      if (j >= 0 && j < n)
        acc += lob[(long)j * lors + nn] * c_SLO[t] + hib[(long)j * hirs + nn] * c_SHI[t];
    }
    out[obase + nn] = acc;
  }
}

// Row-synthesis: lo,hi [H, n, 512] (row stride given) -> out [H, 2n-10, 512] packed
__global__ __launch_bounds__(256) void k_sfb_rows_cl(
    const float* __restrict__ lo, long lors, const float* __restrict__ hi, long hirs,
    float* __restrict__ out, int n, int H, int outW) {
  int blk = blockIdx.x;
  int h = blk / outW, m = blk - h * outW;
  int t0 = 1 - (m & 1);
  const float* lob = lo + (long)h * lors;
  const float* hib = hi + (long)h * hirs;
  long obase = ((long)h * outW + m) * NB;
  for (int nn = threadIdx.x; nn < NB; nn += 256) {
    float acc = 0.f;
#pragma unroll
    for (int s6 = 0; s6 < 6; ++s6) {
      int t = t0 + 2 * s6;
      int j = (m + t - 1) >> 1;
      if (j >= 0 && j < n)
        acc += lob[(long)j * NB + nn] * c_SLO[t] + hib[(long)j * NB + nn] * c_SHI[t];
    }
    out[obase + nn] = acc;
  }
}

// Final level-1 row-synthesis fused with CL -> NCHW transpose.
// lo,hi: [256,133,512] -> out: [512,256,256]
__global__ __launch_bounds__(256) void k_sfb_rows_to_nchw(
    const float* __restrict__ lo, const float* __restrict__ hi, float* __restrict__ out) {
  __shared__ float lds[32 * 257];
  int h = blockIdx.x >> 3;
  int m0 = (blockIdx.x & 7) << 5;
  const float* lob = lo + (long)h * 133 * NB;
  const float* hib = hi + (long)h * 133 * NB;
  for (int c = 0; c < 2; ++c) {
    int n0 = c << 8;
    for (int idx = threadIdx.x; idx < 32 * 256; idx += 256) {
      int ml = idx >> 8, nl = idx & 255;
      int nn = n0 + nl;
      int m = m0 + ml;
      int t0 = 1 - (m & 1);
      float acc = 0.f;
#pragma unroll
      for (int s6 = 0; s6 < 6; ++s6) {
        int t = t0 + 2 * s6;
        int j = (m + t - 1) >> 1;
        if (j >= 0 && j < 133)
          acc += lob[(long)j * NB + nn] * c_SLO[t] + hib[(long)j * NB + nn] * c_SHI[t];
      }
      lds[ml * 257 + nl] = acc;
    }
    __syncthreads();
    for (int idx = threadIdx.x; idx < 32 * 256; idx += 256) {
      int nl = idx >> 5, ml = idx & 31;
      int nn = n0 + nl;
      out[((long)nn * 256 + h) * 256 + m0 + ml] = lds[ml * 257 + nl];
    }
    __syncthreads();
  }
}

// ---------------- weights ----------------

// W [io=4096, yx=4096] -> Wp [yx, io]
__global__ __launch_bounds__(256) void k_transpose_w(
    const float* __restrict__ in, float* __restrict__ out) {
  __shared__ float tile[32][33];
  int bx = blockIdx.x & 127, by = blockIdx.x >> 7;
  int x0 = bx * 32, y0 = by * 32;
  int tx = threadIdx.x & 31, ty = threadIdx.x >> 5;
  for (int r = ty; r < 32; r += 8)
    tile[r][tx] = in[(long)(y0 + r) * 4096 + x0 + tx];
  __syncthreads();
  for (int r = ty; r < 32; r += 8)
    out[(long)(x0 + r) * 4096 + y0 + tx] = tile[tx][r];
}

// ---------------- channel mix (einsum with bilinear-interp weights) ----------------
// One block per pixel. In-place on up to 4 subband arrays (channel-last, 512 contiguous).
__global__ __launch_bounds__(256) void k_mix(
    float* __restrict__ s0, float* __restrict__ s1, float* __restrict__ s2, float* __restrict__ s3,
    int nsub, const float* __restrict__ Wp, int Ho, int Wo) {
  __shared__ float Wm[4096];
  __shared__ float ins[NB];
  int p = blockIdx.x;
  int y = p / Wo, x = p - y * Wo;
  float sy = 64.0f / (float)Ho, sx = 64.0f / (float)Wo;
  float ys = fminf(fmaxf(((float)y + 0.5f) * sy - 0.5f, 0.0f), 63.0f);
  float xs = fminf(fmaxf(((float)x + 0.5f) * sx - 0.5f, 0.0f), 63.0f);
  int y0 = (int)ys, x0 = (int)xs;
  int y1 = min(y0 + 1, 63), x1 = min(x0 + 1, 63);
  float ty = ys - (float)y0, tx = xs - (float)x0;
  float w00 = (1.f - ty) * (1.f - tx), w01 = (1.f - ty) * tx;
  float w10 = ty * (1.f - tx), w11 = ty * tx;
  const float* p00 = Wp + (((long)y0 * 64 + x0) << 12);
  const float* p01 = Wp + (((long)y0 * 64 + x1) << 12);
  const float* p10 = Wp + (((long)y1 * 64 + x0) << 12);
  const float* p11 = Wp + (((long)y1 * 64 + x1) << 12);
  for (int t = threadIdx.x; t < 4096; t += 256)
    Wm[t] = w00 * p00[t] + w01 * p01[t] + w10 * p10[t] + w11 * p11[t];

  long pixoff = ((long)y * Wo + x) * NB;
  int bq = threadIdx.x >> 6;
  int o = threadIdx.x & 63;
  int b0 = bq * 2, b1 = b0 + 1;
  for (int s = 0; s < nsub; ++s) {
    float* base;
    if (s == 0) base = s0; else if (s == 1) base = s1; else if (s == 2) base = s2; else base = s3;
    base += pixoff;
    __syncthreads();  // Wm ready (s=0); previous iter's LDS reads done (s>0)
    for (int t = threadIdx.x; t < NB; t += 256) ins[t] = base[t];
    __syncthreads();
    float a0 = 0.f, a1 = 0.f;
#pragma unroll 16
    for (int i = 0; i < 64; ++i) {
      float w = Wm[(i << 6) + o];
      a0 += ins[(b0 << 6) + i] * w;
      a1 += ins[(b1 << 6) + i] * w;
    }
    base[(b0 << 6) + o] = a0;
    base[(b1 << 6) + o] = a1;
  }
}

// ---------------- driver ----------------

extern "C" void kernel_launch(void* const* d_in, const int* in_sizes, int n_in,
                              void* d_out, int out_size, void* d_ws, size_t ws_size,
                              hipStream_t stream) {
  const float* x = (const float*)d_in[0];
  const float* w = (const float*)d_in[1];
  float* out = (float*)d_out;
  float* ws = (float*)d_ws;

  // workspace layout (floats)
  float* T0  = ws;                 // 17,432,576 = 256*133*512  (also aliases WP)
  float* T1  = ws + 17432576;      // 17,432,576
  float* LL1 = ws + 34865152;      // cap 9,193,472 = 134*134*512 (recon2 reuse)
  float* LH1 = ws + 44058624;      // 9,056,768 each
  float* HL1 = ws + 53115392;
  float* HH1 = ws + 62172160;
  float* LL2 = ws + 71228928;      // 2,654,208 = 72*72*512
  float* LH2 = ws + 73883136;
  float* HL2 = ws + 76537344;
  float* HH2 = ws + 79191552;
  float* LL3 = ws + 81845760;      // 860,672 = 41*41*512
  float* LH3 = ws + 82706432;
  float* HL3 = ws + 83567104;
  float* HH3 = ws + 84427776;
  // total: 85,288,448 floats = 341.2 MB
  float* WP = T0;                  // weights [yx,io]; dead during idwt1 which reclaims T0

  dim3 blk(256);

  // DWT level 1 (256 -> 133)
  k_afb_rows_nchw<<<256 * 16, blk, 0, stream>>>(x, T0, T1);
  k_afb_cols_cl<<<133 * 133, blk, 0, stream>>>(T0, LL1, LH1, 256, 133, 133, 10);
  k_afb_cols_cl<<<133 * 133, blk, 0, stream>>>(T1, HL1, HH1, 256, 133, 133, 10);
  // level 2 (133 -> 72)
  k_afb_rows_cl<<<133 * 72, blk, 0, stream>>>(LL1, T0, T1, 133, 72, 10);
  k_afb_cols_cl<<<72 * 72, blk, 0, stream>>>(T0, LL2, LH2, 133, 72, 72, 10);
  k_afb_cols_cl<<<72 * 72, blk, 0, stream>>>(T1, HL2, HH2, 133, 72, 72, 10);
  // level 3 (72 -> 41)
  k_afb_rows_cl<<<72 * 41, blk, 0, stream>>>(LL2, T0, T1, 72, 41, 10);
  k_afb_cols_cl<<<41 * 41, blk, 0, stream>>>(T0, LL3, LH3, 72, 41, 41, 10);
  k_afb_cols_cl<<<41 * 41, blk, 0, stream>>>(T1, HL3, HH3, 72, 41, 41, 10);

  // weights transpose [io][yx] -> [yx][io]  (into T0, which is free until idwt1)
  k_transpose_w<<<128 * 128, blk, 0, stream>>>(w, WP);

  // channel mixes (in-place)
  k_mix<<<41 * 41, blk, 0, stream>>>(LL3, LH3, HL3, HH3, 4, WP, 41, 41);
  k_mix<<<72 * 72, blk, 0, stream>>>(LH2, HL2, HH2, nullptr, 3, WP, 72, 72);
  k_mix<<<133 * 133, blk, 0, stream>>>(LH1, HL1, HH1, nullptr, 3, WP, 133, 133);

  // IDWT level 3: (41 -> 72), temps in T1
  {
    float* C0 = T1;
    float* C1 = T1 + (long)72 * 41 * NB;  // 1,511,424
    k_sfb_cols_cl<<<72 * 41, blk, 0, stream>>>(LL3, (long)41 * NB, LH3, (long)41 * NB, C0, 41, 41, 72);
    k_sfb_cols_cl<<<72 * 41, blk, 0, stream>>>(HL3, (long)41 * NB, HH3, (long)41 * NB, C1, 41, 41, 72);
    k_sfb_rows_cl<<<72 * 72, blk, 0, stream>>>(C0, (long)41 * NB, C1, (long)41 * NB, LL2, 41, 72, 72);
  }
  // IDWT level 2: (72 -> 134), recon2 into LL1 buffer as [134,134,512]
  {
    float* C0 = T1;
    float* C1 = T1 + (long)134 * 72 * NB;  // 4,939,776
    k_sfb_cols_cl<<<134 * 72, blk, 0, stream>>>(LL2, (long)72 * NB, LH2, (long)72 * NB, C0, 72, 72, 134);
    k_sfb_cols_cl<<<134 * 72, blk, 0, stream>>>(HL2, (long)72 * NB, HH2, (long)72 * NB, C1, 72, 72, 134);
    k_sfb_rows_cl<<<134 * 134, blk, 0, stream>>>(C0, (long)72 * NB, C1, (long)72 * NB, LL1, 72, 134, 134);
  }
  // IDWT level 1: crop recon2 134->133 both dims; (133 -> 256); final fused to NCHW
  {
    k_sfb_cols_cl<<<256 * 133, blk, 0, stream>>>(LL1, (long)134 * NB, LH1, (long)133 * NB, T0, 133, 133, 256);
    k_sfb_cols_cl<<<256 * 133, blk, 0, stream>>>(HL1, (long)133 * NB, HH1, (long)133 * NB, T1, 133, 133, 256);
    k_sfb_rows_to_nchw<<<256 * 8, blk, 0, stream>>>(T0, T1, out);
  }
}

// Round 2
// 1034.256 us; speedup vs baseline: 1.6082x; 1.2664x over previous
//
#include <hip/hip_runtime.h>

// db6 filter taps
#define D0  -0.00107730108499558f
#define D1   0.004777257511010651f
#define D2   0.0005538422009938016f
#define D3  -0.031582039318031156f
#define D4   0.02752286553001629f
#define D5   0.09750160558707936f
#define D6  -0.12976686756709563f
#define D7  -0.22626469396516913f
#define D8   0.3152503517092432f
#define D9   0.7511339080215775f
#define D10  0.4946238903983854f
#define D11  0.11154074335008017f

// a_lo = rec_lo = reversed(dec_lo); a_hi = dec_lo with odd idx negated
// s_lo = dec_lo; s_hi[i] = dec_lo[11-i] * (i even ? -1 : +1)
__constant__ float c_ALO[12] = { D11, D10, D9, D8, D7, D6, D5, D4, D3, D2, D1, D0 };
__constant__ float c_AHI[12] = { D0, -D1, D2, -D3, D4, -D5, D6, -D7, D8, -D9, D10, -D11 };
__constant__ float c_SLO[12] = { D0, D1, D2, D3, D4, D5, D6, D7, D8, D9, D10, D11 };
__constant__ float c_SHI[12] = { -D11, D10, -D9, D8, -D7, D6, -D5, D4, -D3, D2, -D1, D0 };

#define NB 512  // B*C = 8*64

__device__ __forceinline__ void fma4(float4& a, const float4 v, const float c) {
  a.x = fmaf(v.x, c, a.x); a.y = fmaf(v.y, c, a.y);
  a.z = fmaf(v.z, c, a.z); a.w = fmaf(v.w, c, a.w);
}

// ---------------- DWT analysis ----------------

// Level-1 row pass, fused NCHW -> channel-last. x:[512,256,256] -> lo,hi:[256,133,512]
// Block = (h, 32-channel slab). Coalesced float4 loads into LDS (pad 257),
// then float4 outputs: thread = (k, 4-channel group).
__global__ __launch_bounds__(256) void k_afb_rows_nchw(
    const float* __restrict__ x, float4* __restrict__ lo, float4* __restrict__ hi) {
  __shared__ float lds[32][257];
  int h = blockIdx.x >> 4;          // 256 h values
  int n0 = (blockIdx.x & 15) << 5;  // 16 slabs of 32 channels
  for (int idx = threadIdx.x; idx < 32 * 64; idx += 256) {
    int r = idx >> 6, c4 = idx & 63;
    float4 v = *(const float4*)(x + ((long)(n0 + r) * 256 + h) * 256 + (c4 << 2));
    int c = c4 << 2;
    lds[r][c] = v.x; lds[r][c + 1] = v.y; lds[r][c + 2] = v.z; lds[r][c + 3] = v.w;
  }
  __syncthreads();
  int nl4 = threadIdx.x & 7;   // float4 group within 32-channel slab
  int r0 = nl4 << 2;
  for (int k = threadIdx.x >> 3; k < 133; k += 32) {
    int base = 2 * k - 10;
    float4 aL = {0, 0, 0, 0}, aH = {0, 0, 0, 0};
#pragma unroll
    for (int t = 0; t < 12; ++t) {
      int j = base + t;
      j = (j < 0) ? (-j - 1) : ((j >= 256) ? (511 - j) : j);
      float v0 = lds[r0][j], v1 = lds[r0 + 1][j], v2 = lds[r0 + 2][j], v3 = lds[r0 + 3][j];
      float cl = c_ALO[t], ch = c_AHI[t];
      aL.x = fmaf(v0, cl, aL.x); aL.y = fmaf(v1, cl, aL.y);
      aL.z = fmaf(v2, cl, aL.z); aL.w = fmaf(v3, cl, aL.w);
      aH.x = fmaf(v0, ch, aH.x); aH.y = fmaf(v1, ch, aH.y);
      aH.z = fmaf(v2, ch, aH.z); aH.w = fmaf(v3, ch, aH.w);
    }
    long ob = ((long)h * 133 + k) * 128 + (n0 >> 2) + nl4;
    lo[ob] = aL;
    hi[ob] = aH;
  }
}

// Row-analysis on channel-last [H, Win, 512] -> [H, outW, 512]
// 2 pixels per block, 128 float4 lanes each.
__global__ __launch_bounds__(256) void k_afb_rows_cl(
    const float4* __restrict__ in, float4* __restrict__ lo, float4* __restrict__ hi,
    int Win, int outW, int padL, int total) {
  int half = threadIdx.x >> 7, lane = threadIdx.x & 127;
  int p = blockIdx.x * 2 + half;
  if (p >= total) return;
  int h = p / outW, k = p - h * outW;
  int base = 2 * k - padL;
  const float4* rowb = in + (long)h * Win * 128;
  float4 aL = {0, 0, 0, 0}, aH = {0, 0, 0, 0};
#pragma unroll
  for (int t = 0; t < 12; ++t) {
    int j = base + t;
    j = (j < 0) ? (-j - 1) : ((j >= Win) ? (2 * Win - 1 - j) : j);
    float4 v = rowb[(long)j * 128 + lane];
    fma4(aL, v, c_ALO[t]);
    fma4(aH, v, c_AHI[t]);
  }
  long ob = (long)p * 128 + lane;
  lo[ob] = aL;
  hi[ob] = aH;
}

// Column-analysis on channel-last [Hin, W, 512] -> [outH, W, 512]
__global__ __launch_bounds__(256) void k_afb_cols_cl(
    const float4* __restrict__ in, float4* __restrict__ lo, float4* __restrict__ hi,
    int Hin, int W, int padL, int total) {
  int half = threadIdx.x >> 7, lane = threadIdx.x & 127;
  int p = blockIdx.x * 2 + half;
  if (p >= total) return;
  int k = p / W, w = p - k * W;
  int base = 2 * k - padL;
  long rstride = (long)W * 128;
  const float4* colb = in + (long)w * 128;
  float4 aL = {0, 0, 0, 0}, aH = {0, 0, 0, 0};
#pragma unroll
  for (int t = 0; t < 12; ++t) {
    int j = base + t;
    j = (j < 0) ? (-j - 1) : ((j >= Hin) ? (2 * Hin - 1 - j) : j);
    float4 v = colb[(long)j * rstride + lane];
    fma4(aL, v, c_ALO[t]);
    fma4(aH, v, c_AHI[t]);
  }
  long ob = (long)p * 128 + lane;
  lo[ob] = aL;
  hi[ob] = aH;
}

// ---------------- IDWT synthesis ----------------
// out[m] = sum_t u_pad[m+t]*S[t]; u is zero-upsampled (u[2j]=in[j]), pad 1 each side.
// contributing taps: t with (m+t-1) even, j=(m+t-1)/2 in [0,n)
// Strides (lors/hirs) are in float4 units.

// Column-synthesis: lo,hi (rows j, width W, CL) -> out [outH, W, 512] packed
__global__ __launch_bounds__(256) void k_sfb_cols_cl(
    const float4* __restrict__ lo, long lors, const float4* __restrict__ hi, long hirs,
    float4* __restrict__ out, int n, int W, int total) {
  int half = threadIdx.x >> 7, lane = threadIdx.x & 127;
  int p = blockIdx.x * 2 + half;
  if (p >= total) return;
  int m = p / W, w = p - m * W;
  int t0 = 1 - (m & 1);
  const float4* lob = lo + (long)w * 128;
  const float4* hib = hi + (long)w * 128;
  float4 acc = {0, 0, 0, 0};
#pragma unroll
  for (int s6 = 0; s6 < 6; ++s6) {
    int t = t0 + 2 * s6;
    int j = (m + t - 1) >> 1;
    if (j >= 0 && j < n) {
      fma4(acc, lob[(long)j * lors + lane], c_SLO[t]);
      fma4(acc, hib[(long)j * hirs + lane], c_SHI[t]);
    }
  }
  out[(long)p * 128 + lane] = acc;
}

// Row-synthesis: lo,hi [H, n, 512] (h-stride given, f4 units) -> out [H, outW, 512] packed
__global__ __launch_bounds__(256) void k_sfb_rows_cl(
    const float4* __restrict__ lo, long lors, const float4* __restrict__ hi, long hirs,
    float4* __restrict__ out, int n, int outW, int total) {
  int half = threadIdx.x >> 7, lane = threadIdx.x & 127;
  int p = blockIdx.x * 2 + half;
  if (p >= total) return;
  int h = p / outW, m = p - h * outW;
  int t0 = 1 - (m & 1);
  const float4* lob = lo + (long)h * lors;
  const float4* hib = hi + (long)h * hirs;
  float4 acc = {0, 0, 0, 0};
#pragma unroll
  for (int s6 = 0; s6 < 6; ++s6) {
    int t = t0 + 2 * s6;
    int j = (m + t - 1) >> 1;
    if (j >= 0 && j < n) {
      fma4(acc, lob[(long)j * 128 + lane], c_SLO[t]);
      fma4(acc, hib[(long)j * 128 + lane], c_SHI[t]);
    }
  }
  out[(long)p * 128 + lane] = acc;
}

// Final level-1 row-synthesis fused with CL -> NCHW transpose.
// lo,hi: [256,133,512] -> out: [512,256,256]
__global__ __launch_bounds__(256) void k_sfb_rows_to_nchw(
    const float4* __restrict__ lo, const float4* __restrict__ hi, float4* __restrict__ out) {
  __shared__ float lds[32 * 257];
  int h = blockIdx.x >> 3;
  int m0 = (blockIdx.x & 7) << 5;
  const float4* lob = lo + (long)h * 133 * 128;
  const float4* hib = hi + (long)h * 133 * 128;
  for (int c = 0; c < 2; ++c) {
    int n04 = c << 6;  // float4 offset of this 256-channel half
    for (int idx = threadIdx.x; idx < 32 * 64; idx += 256) {
      int ml = idx >> 6, nl4 = idx & 63;
      int m = m0 + ml;
      int t0 = 1 - (m & 1);
      float4 acc = {0, 0, 0, 0};
#pragma unroll
      for (int s6 = 0; s6 < 6; ++s6) {
        int t = t0 + 2 * s6;
        int j = (m + t - 1) >> 1;
        if (j >= 0 && j < 133) {
          fma4(acc, lob[(long)j * 128 + n04 + nl4], c_SLO[t]);
          fma4(acc, hib[(long)j * 128 + n04 + nl4], c_SHI[t]);
        }
      }
      int cb = ml * 257 + (nl4 << 2);
      lds[cb] = acc.x; lds[cb + 1] = acc.y; lds[cb + 2] = acc.z; lds[cb + 3] = acc.w;
    }
    __syncthreads();
    int ml4 = threadIdx.x & 7;
    for (int nl = threadIdx.x >> 3; nl < 256; nl += 32) {
      int nn = (c << 8) + nl;
      float4 v;
      v.x = lds[(ml4 * 4 + 0) * 257 + nl];
      v.y = lds[(ml4 * 4 + 1) * 257 + nl];
      v.z = lds[(ml4 * 4 + 2) * 257 + nl];
      v.w = lds[(ml4 * 4 + 3) * 257 + nl];
      out[((long)nn * 256 + h) * 64 + (m0 >> 2) + ml4] = v;
    }
    __syncthreads();
  }
}

// ---------------- weights ----------------

// W [io=4096, yx=4096] -> Wp [yx, io]
__global__ __launch_bounds__(256) void k_transpose_w(
    const float* __restrict__ in, float* __restrict__ out) {
  __shared__ float tile[32][33];
  int bx = blockIdx.x & 127, by = blockIdx.x >> 7;
  int x0 = bx * 32, y0 = by * 32;
  int tx = threadIdx.x & 31, ty = threadIdx.x >> 5;
  for (int r = ty; r < 32; r += 8)
    tile[r][tx] = in[(long)(y0 + r) * 4096 + x0 + tx];
  __syncthreads();
  for (int r = ty; r < 32; r += 8)
    out[(long)(x0 + r) * 4096 + y0 + tx] = tile[tx][r];
}

// ---------------- channel mix (einsum with bilinear-interp weights) ----------------
// One block per pixel. In-place on up to 4 subband arrays (channel-last, 512 contiguous).
__global__ __launch_bounds__(256) void k_mix(
    float* __restrict__ s0, float* __restrict__ s1, float* __restrict__ s2, float* __restrict__ s3,
    int nsub, const float* __restrict__ Wp, int Ho, int Wo) {
  __shared__ float Wm[4096];
  __shared__ float ins[NB];
  int p = blockIdx.x;
  int y = p / Wo, x = p - y * Wo;
  float sy = 64.0f / (float)Ho, sx = 64.0f / (float)Wo;
  float ys = fminf(fmaxf(((float)y + 0.5f) * sy - 0.5f, 0.0f), 63.0f);
  float xs = fminf(fmaxf(((float)x + 0.5f) * sx - 0.5f, 0.0f), 63.0f);
  int y0 = (int)ys, x0 = (int)xs;
  int y1 = min(y0 + 1, 63), x1 = min(x0 + 1, 63);
  float ty = ys - (float)y0, tx = xs - (float)x0;
  float w00 = (1.f - ty) * (1.f - tx), w01 = (1.f - ty) * tx;
  float w10 = ty * (1.f - tx), w11 = ty * tx;
  const float4* p00 = (const float4*)(Wp + (((long)y0 * 64 + x0) << 12));
  const float4* p01 = (const float4*)(Wp + (((long)y0 * 64 + x1) << 12));
  const float4* p10 = (const float4*)(Wp + (((long)y1 * 64 + x0) << 12));
  const float4* p11 = (const float4*)(Wp + (((long)y1 * 64 + x1) << 12));
  float4* Wm4 = (float4*)Wm;
  for (int t = threadIdx.x; t < 1024; t += 256) {
    float4 a = p00[t], b = p01[t], c = p10[t], d = p11[t];
    float4 r;
    r.x = w00 * a.x + w01 * b.x + w10 * c.x + w11 * d.x;
    r.y = w00 * a.y + w01 * b.y + w10 * c.y + w11 * d.y;
    r.z = w00 * a.z + w01 * b.z + w10 * c.z + w11 * d.z;
    r.w = w00 * a.w + w01 * b.w + w10 * c.w + w11 * d.w;
    Wm4[t] = r;
  }

  long pixoff = ((long)y * Wo + x) * NB;
  int bq = threadIdx.x >> 6;
  int o = threadIdx.x & 63;
  int b0 = bq * 2, b1 = b0 + 1;
  for (int s = 0; s < nsub; ++s) {
    float* base;
    if (s == 0) base = s0; else if (s == 1) base = s1; else if (s == 2) base = s2; else base = s3;
    base += pixoff;
    __syncthreads();  // Wm ready (s=0); previous iter's LDS reads done (s>0)
    if (threadIdx.x < 128)
      ((float4*)ins)[threadIdx.x] = ((const float4*)base)[threadIdx.x];
    __syncthreads();
    float a0 = 0.f, a1 = 0.f;
#pragma unroll 16
    for (int i = 0; i < 64; ++i) {
      float w = Wm[(i << 6) + o];
      a0 += ins[(b0 << 6) + i] * w;
      a1 += ins[(b1 << 6) + i] * w;
    }
    base[(b0 << 6) + o] = a0;
    base[(b1 << 6) + o] = a1;
  }
}

// ---------------- driver ----------------

extern "C" void kernel_launch(void* const* d_in, const int* in_sizes, int n_in,
                              void* d_out, int out_size, void* d_ws, size_t ws_size,
                              hipStream_t stream) {
  const float* x = (const float*)d_in[0];
  const float* w = (const float*)d_in[1];
  float4* out = (float4*)d_out;
  float* ws = (float*)d_ws;

  // workspace layout (floats)
  float* T0  = ws;                 // 17,432,576 = 256*133*512  (also aliases WP)
  float* T1  = ws + 17432576;      // 17,432,576
  float* LL1 = ws + 34865152;      // cap 9,193,472 = 134*134*512 (recon2 reuse)
  float* LH1 = ws + 44058624;      // 9,056,768 each
  float* HL1 = ws + 53115392;
  float* HH1 = ws + 62172160;
  float* LL2 = ws + 71228928;      // 2,654,208 = 72*72*512
  float* LH2 = ws + 73883136;
  float* HL2 = ws + 76537344;
  float* HH2 = ws + 79191552;
  float* LL3 = ws + 81845760;      // 860,672 = 41*41*512
  float* LH3 = ws + 82706432;
  float* HL3 = ws + 83567104;
  float* HH3 = ws + 84427776;
  // total: 85,288,448 floats = 341.2 MB
  float* WP = T0;                  // weights [yx,io]; dead during idwt1 which reclaims T0

#define F4(p) ((float4*)(p))
  dim3 blk(256);

  // DWT level 1 (256 -> 133)
  k_afb_rows_nchw<<<256 * 16, blk, 0, stream>>>(x, F4(T0), F4(T1));
  k_afb_cols_cl<<<(133 * 133 + 1) / 2, blk, 0, stream>>>(F4(T0), F4(LL1), F4(LH1), 256, 133, 10, 133 * 133);
  k_afb_cols_cl<<<(133 * 133 + 1) / 2, blk, 0, stream>>>(F4(T1), F4(HL1), F4(HH1), 256, 133, 10, 133 * 133);
  // level 2 (133 -> 72)
  k_afb_rows_cl<<<(133 * 72 + 1) / 2, blk, 0, stream>>>(F4(LL1), F4(T0), F4(T1), 133, 72, 10, 133 * 72);
  k_afb_cols_cl<<<(72 * 72 + 1) / 2, blk, 0, stream>>>(F4(T0), F4(LL2), F4(LH2), 133, 72, 10, 72 * 72);
  k_afb_cols_cl<<<(72 * 72 + 1) / 2, blk, 0, stream>>>(F4(T1), F4(HL2), F4(HH2), 133, 72, 10, 72 * 72);
  // level 3 (72 -> 41)
  k_afb_rows_cl<<<(72 * 41 + 1) / 2, blk, 0, stream>>>(F4(LL2), F4(T0), F4(T1), 72, 41, 10, 72 * 41);
  k_afb_cols_cl<<<(41 * 41 + 1) / 2, blk, 0, stream>>>(F4(T0), F4(LL3), F4(LH3), 72, 41, 10, 41 * 41);
  k_afb_cols_cl<<<(41 * 41 + 1) / 2, blk, 0, stream>>>(F4(T1), F4(HL3), F4(HH3), 72, 41, 10, 41 * 41);

  // weights transpose [io][yx] -> [yx][io]  (into T0, which is free until idwt1)
  k_transpose_w<<<128 * 128, blk, 0, stream>>>(w, WP);

  // channel mixes (in-place)
  k_mix<<<41 * 41, blk, 0, stream>>>(LL3, LH3, HL3, HH3, 4, WP, 41, 41);
  k_mix<<<72 * 72, blk, 0, stream>>>(LH2, HL2, HH2, nullptr, 3, WP, 72, 72);
  k_mix<<<133 * 133, blk, 0, stream>>>(LH1, HL1, HH1, nullptr, 3, WP, 133, 133);

  // IDWT level 3: (41 -> 72), temps in T1
  {
    float* C0 = T1;
    float* C1 = T1 + (long)72 * 41 * NB;  // 1,511,424
    k_sfb_cols_cl<<<(72 * 41 + 1) / 2, blk, 0, stream>>>(F4(LL3), 41 * 128, F4(LH3), 41 * 128, F4(C0), 41, 41, 72 * 41);
    k_sfb_cols_cl<<<(72 * 41 + 1) / 2, blk, 0, stream>>>(F4(HL3), 41 * 128, F4(HH3), 41 * 128, F4(C1), 41, 41, 72 * 41);
    k_sfb_rows_cl<<<(72 * 72 + 1) / 2, blk, 0, stream>>>(F4(C0), 41 * 128, F4(C1), 41 * 128, F4(LL2), 41, 72, 72 * 72);
  }
  // IDWT level 2: (72 -> 134), recon2 into LL1 buffer as [134,134,512]
  {
    float* C0 = T1;
    float* C1 = T1 + (long)134 * 72 * NB;  // 4,939,776
    k_sfb_cols_cl<<<(134 * 72 + 1) / 2, blk, 0, stream>>>(F4(LL2), 72 * 128, F4(LH2), 72 * 128, F4(C0), 72, 72, 134 * 72);
    k_sfb_cols_cl<<<(134 * 72 + 1) / 2, blk, 0, stream>>>(F4(HL2), 72 * 128, F4(HH2), 72 * 128, F4(C1), 72, 72, 134 * 72);
    k_sfb_rows_cl<<<(134 * 134 + 1) / 2, blk, 0, stream>>>(F4(C0), 72 * 128, F4(C1), 72 * 128, F4(LL1), 72, 134, 134 * 134);
  }
  // IDWT level 1: crop recon2 134->133 both dims; (133 -> 256); final fused to NCHW
  {
    k_sfb_cols_cl<<<(256 * 133 + 1) / 2, blk, 0, stream>>>(F4(LL1), 134 * 128, F4(LH1), 133 * 128, F4(T0), 133, 133, 256 * 133);
    k_sfb_cols_cl<<<(256 * 133 + 1) / 2, blk, 0, stream>>>(F4(HL1), 133 * 128, F4(HH1), 133 * 128, F4(T1), 133, 133, 256 * 133);
    k_sfb_rows_to_nchw<<<256 * 8, blk, 0, stream>>>(F4(T0), F4(T1), out);
  }
#undef F4
}